// Round 3
// baseline (282.137 us; speedup 1.0000x reference)
//
#include <hip/hip_runtime.h>

#define D_MODEL 1024
#define NHEAD 16
#define DK 64
#define SEQ 2048
#define NBATCH 2
#define MROWS (NBATCH * SEQ)   // 4096

typedef unsigned short u16;
typedef short bf16x8 __attribute__((ext_vector_type(8)));   // 8 bf16 = 4 VGPR
typedef float f32x4 __attribute__((ext_vector_type(4)));
typedef unsigned short u16x8 __attribute__((ext_vector_type(8)));

__device__ __forceinline__ u16 f2bf(float f) {
    union { float f; unsigned u; } v; v.f = f;
    unsigned r = v.u + 0x7FFFu + ((v.u >> 16) & 1u);   // RNE
    return (u16)(r >> 16);
}

__device__ __forceinline__ void gload16(const void* g, void* s) {
    __builtin_amdgcn_global_load_lds((const __attribute__((address_space(1))) void*)g,
                                     (__attribute__((address_space(3))) void*)s, 16, 0, 0);
}

// ---------------- fp32 -> bf16 conversion (x, Wq|Wk|Wv stacked, Wo) ----------------
#define XN 4194304   // 4096*1024
#define WN 1048576   // 1024*1024

__global__ __launch_bounds__(256) void convert_bf16(
    const float* __restrict__ x, const float* __restrict__ wq, const float* __restrict__ wk,
    const float* __restrict__ wv, const float* __restrict__ wo,
    u16* __restrict__ xb, u16* __restrict__ wqkv, u16* __restrict__ wob)
{
    size_t base = ((size_t)blockIdx.x * 256 + threadIdx.x) * 8;
    const float* src; u16* dst;
    if (base < XN)               { src = x  + base;                dst = xb   + base; }
    else if (base < XN + WN)     { src = wq + (base - XN);         dst = wqkv + (base - XN); }
    else if (base < XN + 2*WN)   { src = wk + (base - XN - WN);    dst = wqkv + (base - XN); }
    else if (base < XN + 3*WN)   { src = wv + (base - XN - 2*WN);  dst = wqkv + (base - XN); }
    else                         { src = wo + (base - XN - 3*WN);  dst = wob  + (base - XN - 3*WN); }
    float4 a = *(const float4*)&src[0];
    float4 b = *(const float4*)&src[4];
    u16x8 o;
    o[0] = f2bf(a.x); o[1] = f2bf(a.y); o[2] = f2bf(a.z); o[3] = f2bf(a.w);
    o[4] = f2bf(b.x); o[5] = f2bf(b.y); o[6] = f2bf(b.z); o[7] = f2bf(b.w);
    *(u16x8*)dst = o;
}

// ---------------- QKV GEMM (M=4096, N=3072, K=1024) + RoPE epilogue ----------------
// 2-phase pipelined (double-buffered LDS, one barrier per K-step).
// q,k out: (B,H,S,DK) bf16, q scaled by 0.125.  v out: (B,H,DK,S) bf16 (transposed).
__global__ __launch_bounds__(256) void gemm_qkv(
    const u16* __restrict__ A, const u16* __restrict__ B,
    u16* __restrict__ qo, u16* __restrict__ ko, u16* __restrict__ vo)
{
    __shared__ __align__(16) u16 sbuf[17408];   // dbuf 2x(As 4096 + Bs 4096); epilogue scratch 4*64*68

    const int tid = threadIdx.x, w = tid >> 6, l = tid & 63;
    const int l15 = l & 15, lg = l >> 4;
    const int m0 = blockIdx.x * 128, n0 = blockIdx.y * 128;
    const int wm = (w >> 1) * 64, wn = (w & 1) * 64;

    f32x4 zero = {0.f, 0.f, 0.f, 0.f};
    f32x4 acc[4][4];
#pragma unroll
    for (int i = 0; i < 4; ++i)
#pragma unroll
        for (int j = 0; j < 4; ++j) acc[i][j] = zero;

    auto stage = [&](int k0s, int half) {
        const int hb = half * 8192;
#pragma unroll
        for (int it = 0; it < 2; ++it) {
            int ubase = it * 256 + w * 64;
            int u = ubase + l, row = u >> 2, kq = u & 3;
            gload16(A + (size_t)(m0 + row) * D_MODEL + k0s + kq * 8, &sbuf[hb + ubase * 8]);
        }
#pragma unroll
        for (int it = 0; it < 2; ++it) {
            int ubase = it * 256 + w * 64;
            int u = ubase + l, row = u >> 2, kq = u & 3;
            gload16(B + (size_t)(n0 + row) * D_MODEL + k0s + kq * 8, &sbuf[hb + 4096 + ubase * 8]);
        }
    };

    stage(0, 0);
    int cur = 0;
    for (int k0 = 0; k0 < D_MODEL; k0 += 32, cur ^= 1) {
        __syncthreads();                       // buf[cur] staged (vmcnt drained here)
        if (k0 + 32 < D_MODEL) stage(k0 + 32, cur ^ 1);
        const int hb = cur * 8192;
        bf16x8 af[4], bf[4];
#pragma unroll
        for (int mi = 0; mi < 4; ++mi) af[mi] = *(const bf16x8*)&sbuf[hb + (wm + mi * 16 + l15) * 32 + lg * 8];
#pragma unroll
        for (int ni = 0; ni < 4; ++ni) bf[ni] = *(const bf16x8*)&sbuf[hb + 4096 + (wn + ni * 16 + l15) * 32 + lg * 8];
#pragma unroll
        for (int mi = 0; mi < 4; ++mi)
#pragma unroll
            for (int ni = 0; ni < 4; ++ni)
                acc[mi][ni] = __builtin_amdgcn_mfma_f32_16x16x32_bf16(af[mi], bf[ni], acc[mi][ni], 0, 0, 0);
    }

    const int which = n0 >> 10;   // 0=q 1=k 2=v (block-uniform)
    if (which < 2) {
        u16* outp = (which == 0) ? qo : ko;
        const float lnth = 9.210340371976184f;   // ln(10000)
#pragma unroll
        for (int ni = 0; ni < 4; ++ni) {
            int n = n0 + wn + ni * 16 + l15;
            int hh = (n >> 6) & 15, d = n & 63;
            float invf = __expf(-lnth * (float)(d & 62) * (1.0f / 64.0f));
            float sgn = (d & 1) ? 1.0f : -1.0f;
#pragma unroll
            for (int mi = 0; mi < 4; ++mi) {
#pragma unroll
                for (int i = 0; i < 4; ++i) {
                    int m = m0 + wm + mi * 16 + lg * 4 + i;
                    int bb = m >> 11, s = m & (SEQ - 1);
                    float v = acc[mi][ni][i];
                    float pv = __shfl_xor(v, 1);
                    float sn, cs;
                    __sincosf((float)s * invf, &sn, &cs);
                    float res = v * cs + sgn * pv * sn;
                    if (which == 0) res *= 0.125f;   // 1/sqrt(dk), exact
                    outp[((size_t)(bb * NHEAD + hh) * SEQ + s) * DK + d] = f2bf(res);
                }
            }
        }
    } else {
        // V: per-wave LDS transpose, write (B,H,DK,S)
        __syncthreads();   // staging buffers dead
        u16* sc = &sbuf[w * 64 * 68];
#pragma unroll
        for (int mi = 0; mi < 4; ++mi)
#pragma unroll
            for (int ni = 0; ni < 4; ++ni)
#pragma unroll
                for (int i = 0; i < 4; ++i)
                    sc[(mi * 16 + lg * 4 + i) * 68 + ni * 16 + l15] = f2bf(acc[mi][ni][i]);
        int vcol = n0 - 2048 + wn;          // multiple of 64
        int hh = vcol >> 6;
        int m = m0 + wm, bb = m >> 11, s0 = m & (SEQ - 1);
        u16* dst = vo + ((size_t)(bb * NHEAD + hh) * DK + l) * SEQ + s0;
#pragma unroll
        for (int j8 = 0; j8 < 8; ++j8) {
            u16x8 val;
#pragma unroll
            for (int jj = 0; jj < 8; ++jj) val[jj] = sc[(j8 * 8 + jj) * 68 + l];
            *(u16x8*)&dst[j8 * 8] = val;
        }
    }
}

// ---------------- Flash attention, causal, bf16 MFMA, barrier-free ----------------
// 4 independent waves x 16 q-rows. K/V B-fragments load directly from global (L2/L3-
// resident); only LDS use is the per-wave P transpose bounce. No __syncthreads at all.
__global__ __launch_bounds__(256) void attn_mfma(
    const u16* __restrict__ qb, const u16* __restrict__ kb,
    const u16* __restrict__ vtb, u16* __restrict__ attnb)
{
    __shared__ __align__(16) u16 Ps_all[4096];   // 4 waves x 16 rows x 64 cols

    const int bh = blockIdx.x;                   // bh fast: uniform-cost block waves
    const int b = bh >> 4, h = bh & 15;
    const int qt = (SEQ / 64 - 1) - blockIdx.y;  // big blocks launch first
    const int qbase = qt * 64;
    const int tid = threadIdx.x, w = tid >> 6, l = tid & 63;
    const int l15 = l & 15, lg = l >> 4;

    // Q A-fragments direct from global: row=l15, k=lg*8..+7
    const u16* qrow = qb + ((size_t)bh * SEQ + qbase + w * 16 + l15) * DK;
    bf16x8 aq[2];
    aq[0] = *(const bf16x8*)&qrow[lg * 8];
    aq[1] = *(const bf16x8*)&qrow[32 + lg * 8];

    f32x4 zero = {0.f, 0.f, 0.f, 0.f};
    f32x4 of[4];
#pragma unroll
    for (int i = 0; i < 4; ++i) of[i] = zero;
    float mrun[4] = {-1e30f, -1e30f, -1e30f, -1e30f};
    float lrun[4] = {0.f, 0.f, 0.f, 0.f};

    const u16* kbase = kb + ((size_t)bh * SEQ + l15) * DK + lg * 8;      // + kt*4096 + ni*1024 + kk*32
    const u16* vbase = vtb + ((size_t)(bh * DK) + l15) * SEQ + lg * 8;   // + n2*16*SEQ + kt*64 + kk*32
    u16* Ps = &Ps_all[w * 1024];

    for (int kt = 0; kt <= qt; ++kt) {
        // ---- QK^T: S[16q][64k], K B-frags from global ----
        const u16* kp = kbase + (size_t)kt * 64 * DK;
        f32x4 s4[4];
#pragma unroll
        for (int ni = 0; ni < 4; ++ni) {
            s4[ni] = zero;
#pragma unroll
            for (int kk = 0; kk < 2; ++kk) {
                bf16x8 bk = *(const bf16x8*)&kp[ni * 16 * DK + kk * 32];
                s4[ni] = __builtin_amdgcn_mfma_f32_16x16x32_bf16(aq[kk], bk, s4[ni], 0, 0, 0);
            }
        }
        if (kt == qt) {   // diagonal tile mask
#pragma unroll
            for (int ni = 0; ni < 4; ++ni)
#pragma unroll
                for (int i = 0; i < 4; ++i)
                    if (ni * 16 + l15 > w * 16 + lg * 4 + i) s4[ni][i] = -1e30f;
        }

        // ---- online softmax (row spread over 16 lanes of same lg group) ----
        float scl[4], rsum[4];
#pragma unroll
        for (int i = 0; i < 4; ++i) {
            float t = fmaxf(fmaxf(s4[0][i], s4[1][i]), fmaxf(s4[2][i], s4[3][i]));
#pragma unroll
            for (int msk = 1; msk < 16; msk <<= 1) t = fmaxf(t, __shfl_xor(t, msk));
            float mn = fmaxf(mrun[i], t);
            scl[i] = __expf(mrun[i] - mn);
            mrun[i] = mn;
            rsum[i] = 0.f;
        }
#pragma unroll
        for (int ni = 0; ni < 4; ++ni)
#pragma unroll
            for (int i = 0; i < 4; ++i) {
                float p = __expf(s4[ni][i] - mrun[i]);
                rsum[i] += p;
                int q = lg * 4 + i;
                int colb = ni * 32 + l15 * 2;
                Ps[q * 64 + ((colb ^ ((q & 7) << 4)) >> 1)] = f2bf(p);
            }
#pragma unroll
        for (int i = 0; i < 4; ++i) {
#pragma unroll
            for (int msk = 1; msk < 16; msk <<= 1) rsum[i] += __shfl_xor(rsum[i], msk);
            lrun[i] = lrun[i] * scl[i] + rsum[i];
        }
        // rescale O
#pragma unroll
        for (int n2 = 0; n2 < 4; ++n2)
#pragma unroll
            for (int i = 0; i < 4; ++i) of[n2][i] *= scl[i];

        // ---- P A-frags from own (wave-local) Ps region ----
        bf16x8 ap[2];
#pragma unroll
        for (int kk = 0; kk < 2; ++kk) {
            int q = l15;
            int cb = (kk * 64 + lg * 16) ^ ((q & 7) << 4);
            ap[kk] = *(const bf16x8*)&Ps[q * 64 + (cb >> 1)];
        }

        // ---- PV: O[16q][64d], V^T B-frags from global ----
        const u16* vp = vbase + kt * 64;
#pragma unroll
        for (int n2 = 0; n2 < 4; ++n2)
#pragma unroll
            for (int kk = 0; kk < 2; ++kk) {
                bf16x8 bv = *(const bf16x8*)&vp[n2 * 16 * SEQ + kk * 32];
                of[n2] = __builtin_amdgcn_mfma_f32_16x16x32_bf16(ap[kk], bv, of[n2], 0, 0, 0);
            }
    }

    // epilogue: O/l -> attn (B,S,D) bf16
#pragma unroll
    for (int n2 = 0; n2 < 4; ++n2)
#pragma unroll
        for (int i = 0; i < 4; ++i) {
            int qrow2 = qbase + w * 16 + lg * 4 + i;
            int d = n2 * 16 + l15;
            float res = of[n2][i] / lrun[i];
            attnb[((size_t)(b * SEQ + qrow2)) * D_MODEL + h * DK + d] = f2bf(res);
        }
}

// ---------------- Output projection GEMM (M=4096, N=1024, K=1024), fp32 out ----------------
// 2-phase pipelined (double-buffered LDS, one barrier per K-step).
__global__ __launch_bounds__(256) void gemm_proj(
    const u16* __restrict__ A, const u16* __restrict__ B, float* __restrict__ out)
{
    __shared__ __align__(16) u16 sbuf[16384];   // dbuf 2x(As 4096 + Bs 4096)

    const int tid = threadIdx.x, w = tid >> 6, l = tid & 63;
    const int l15 = l & 15, lg = l >> 4;
    const int m0 = blockIdx.x * 128, n0 = blockIdx.y * 128;
    const int wm = (w >> 1) * 64, wn = (w & 1) * 64;

    f32x4 zero = {0.f, 0.f, 0.f, 0.f};
    f32x4 acc[4][4];
#pragma unroll
    for (int i = 0; i < 4; ++i)
#pragma unroll
        for (int j = 0; j < 4; ++j) acc[i][j] = zero;

    auto stage = [&](int k0s, int half) {
        const int hb = half * 8192;
#pragma unroll
        for (int it = 0; it < 2; ++it) {
            int ubase = it * 256 + w * 64;
            int u = ubase + l, row = u >> 2, kq = u & 3;
            gload16(A + (size_t)(m0 + row) * D_MODEL + k0s + kq * 8, &sbuf[hb + ubase * 8]);
        }
#pragma unroll
        for (int it = 0; it < 2; ++it) {
            int ubase = it * 256 + w * 64;
            int u = ubase + l, row = u >> 2, kq = u & 3;
            gload16(B + (size_t)(n0 + row) * D_MODEL + k0s + kq * 8, &sbuf[hb + 4096 + ubase * 8]);
        }
    };

    stage(0, 0);
    int cur = 0;
    for (int k0 = 0; k0 < D_MODEL; k0 += 32, cur ^= 1) {
        __syncthreads();
        if (k0 + 32 < D_MODEL) stage(k0 + 32, cur ^ 1);
        const int hb = cur * 8192;
        bf16x8 af[4], bf[4];
#pragma unroll
        for (int mi = 0; mi < 4; ++mi) af[mi] = *(const bf16x8*)&sbuf[hb + (wm + mi * 16 + l15) * 32 + lg * 8];
#pragma unroll
        for (int ni = 0; ni < 4; ++ni) bf[ni] = *(const bf16x8*)&sbuf[hb + 4096 + (wn + ni * 16 + l15) * 32 + lg * 8];
#pragma unroll
        for (int mi = 0; mi < 4; ++mi)
#pragma unroll
            for (int ni = 0; ni < 4; ++ni)
                acc[mi][ni] = __builtin_amdgcn_mfma_f32_16x16x32_bf16(af[mi], bf[ni], acc[mi][ni], 0, 0, 0);
    }

#pragma unroll
    for (int mi = 0; mi < 4; ++mi)
#pragma unroll
        for (int ni = 0; ni < 4; ++ni)
#pragma unroll
            for (int i = 0; i < 4; ++i) {
                int m = m0 + wm + mi * 16 + lg * 4 + i;
                int n = n0 + wn + ni * 16 + l15;
                out[(size_t)m * D_MODEL + n] = acc[mi][ni][i];
            }
}

extern "C" void kernel_launch(void* const* d_in, const int* in_sizes, int n_in,
                              void* d_out, int out_size, void* d_ws, size_t ws_size,
                              hipStream_t stream) {
    const float* x  = (const float*)d_in[0];
    const float* Wq = (const float*)d_in[1];
    const float* Wk = (const float*)d_in[2];
    const float* Wv = (const float*)d_in[3];
    const float* Wo = (const float*)d_in[4];
    float* out = (float*)d_out;

    u16* ws = (u16*)d_ws;
    const size_t M1 = 1048576;
    u16* xb    = ws;            // 4M u16
    u16* wqkv  = ws + 4 * M1;   // 3M  (Wq|Wk|Wv rows stacked)
    u16* wob   = ws + 7 * M1;   // 1M
    u16* qb    = ws + 8 * M1;   // 4M (B,H,S,DK), scaled by 1/8
    u16* kb    = ws + 12 * M1;  // 4M (B,H,S,DK)
    u16* vtb   = ws + 16 * M1;  // 4M (B,H,DK,S)
    u16* attnb = ws + 20 * M1;  // 4M (B,S,D)

    convert_bf16<<<dim3(4096), dim3(256), 0, stream>>>(x, Wq, Wk, Wv, Wo, xb, wqkv, wob);
    gemm_qkv<<<dim3(MROWS / 128, 3072 / 128), dim3(256), 0, stream>>>(xb, wqkv, qb, kb, vtb);
    attn_mfma<<<dim3(NBATCH * NHEAD, SEQ / 64), dim3(256), 0, stream>>>(qb, kb, vtb, attnb);
    gemm_proj<<<dim3(MROWS / 128, D_MODEL / 128), dim3(256), 0, stream>>>(attnb, wob, out);
}

// Round 5
// 264.409 us; speedup vs baseline: 1.0670x; 1.0670x over previous
//
#include <hip/hip_runtime.h>

#define D_MODEL 1024
#define NHEAD 16
#define DK 64
#define SEQ 2048
#define NBATCH 2
#define MROWS (NBATCH * SEQ)   // 4096

typedef unsigned short u16;
typedef short bf16x8 __attribute__((ext_vector_type(8)));   // 8 bf16 = 4 VGPR
typedef float f32x4 __attribute__((ext_vector_type(4)));
typedef unsigned short u16x8 __attribute__((ext_vector_type(8)));

__device__ __forceinline__ u16 f2bf(float f) {
    union { float f; unsigned u; } v; v.f = f;
    unsigned r = v.u + 0x7FFFu + ((v.u >> 16) & 1u);   // RNE
    return (u16)(r >> 16);
}

__device__ __forceinline__ void gload16(const void* g, void* s) {
    __builtin_amdgcn_global_load_lds((const __attribute__((address_space(1))) void*)g,
                                     (__attribute__((address_space(3))) void*)s, 16, 0, 0);
}

// ---------------- fp32 -> bf16 conversion (x, Wq|Wk|Wv stacked, Wo) ----------------
#define XN 4194304   // 4096*1024
#define WN 1048576   // 1024*1024

__global__ __launch_bounds__(256) void convert_bf16(
    const float* __restrict__ x, const float* __restrict__ wq, const float* __restrict__ wk,
    const float* __restrict__ wv, const float* __restrict__ wo,
    u16* __restrict__ xb, u16* __restrict__ wqkv, u16* __restrict__ wob)
{
    size_t base = ((size_t)blockIdx.x * 256 + threadIdx.x) * 8;
    const float* src; u16* dst;
    if (base < XN)               { src = x  + base;                dst = xb   + base; }
    else if (base < XN + WN)     { src = wq + (base - XN);         dst = wqkv + (base - XN); }
    else if (base < XN + 2*WN)   { src = wk + (base - XN - WN);    dst = wqkv + (base - XN); }
    else if (base < XN + 3*WN)   { src = wv + (base - XN - 2*WN);  dst = wqkv + (base - XN); }
    else                         { src = wo + (base - XN - 3*WN);  dst = wob  + (base - XN - 3*WN); }
    float4 a = *(const float4*)&src[0];
    float4 b = *(const float4*)&src[4];
    u16x8 o;
    o[0] = f2bf(a.x); o[1] = f2bf(a.y); o[2] = f2bf(a.z); o[3] = f2bf(a.w);
    o[4] = f2bf(b.x); o[5] = f2bf(b.y); o[6] = f2bf(b.z); o[7] = f2bf(b.w);
    *(u16x8*)dst = o;
}

// ---------------- QKV GEMM (M=4096, N=3072, K=1024) + RoPE epilogue ----------------
// 2-phase pipelined (double-buffered LDS, one barrier per K-step).
// q,k out: (B,H,S,DK) bf16, q scaled by 0.125.  v out: (B,H,DK,S) bf16 (transposed).
__global__ __launch_bounds__(256) void gemm_qkv(
    const u16* __restrict__ A, const u16* __restrict__ B,
    u16* __restrict__ qo, u16* __restrict__ ko, u16* __restrict__ vo)
{
    __shared__ __align__(16) u16 sbuf[17408];   // dbuf 2x(As 4096 + Bs 4096); epilogue scratch 4*64*68

    const int tid = threadIdx.x, w = tid >> 6, l = tid & 63;
    const int l15 = l & 15, lg = l >> 4;
    const int m0 = blockIdx.x * 128, n0 = blockIdx.y * 128;
    const int wm = (w >> 1) * 64, wn = (w & 1) * 64;

    f32x4 zero = {0.f, 0.f, 0.f, 0.f};
    f32x4 acc[4][4];
#pragma unroll
    for (int i = 0; i < 4; ++i)
#pragma unroll
        for (int j = 0; j < 4; ++j) acc[i][j] = zero;

    auto stage = [&](int k0s, int half) {
        const int hb = half * 8192;
#pragma unroll
        for (int it = 0; it < 2; ++it) {
            int ubase = it * 256 + w * 64;
            int u = ubase + l, row = u >> 2, kq = u & 3;
            gload16(A + (size_t)(m0 + row) * D_MODEL + k0s + kq * 8, &sbuf[hb + ubase * 8]);
        }
#pragma unroll
        for (int it = 0; it < 2; ++it) {
            int ubase = it * 256 + w * 64;
            int u = ubase + l, row = u >> 2, kq = u & 3;
            gload16(B + (size_t)(n0 + row) * D_MODEL + k0s + kq * 8, &sbuf[hb + 4096 + ubase * 8]);
        }
    };

    stage(0, 0);
    int cur = 0;
    for (int k0 = 0; k0 < D_MODEL; k0 += 32, cur ^= 1) {
        __syncthreads();                       // buf[cur] staged (vmcnt drained here)
        if (k0 + 32 < D_MODEL) stage(k0 + 32, cur ^ 1);
        const int hb = cur * 8192;
        bf16x8 af[4], bf[4];
#pragma unroll
        for (int mi = 0; mi < 4; ++mi) af[mi] = *(const bf16x8*)&sbuf[hb + (wm + mi * 16 + l15) * 32 + lg * 8];
#pragma unroll
        for (int ni = 0; ni < 4; ++ni) bf[ni] = *(const bf16x8*)&sbuf[hb + 4096 + (wn + ni * 16 + l15) * 32 + lg * 8];
#pragma unroll
        for (int mi = 0; mi < 4; ++mi)
#pragma unroll
            for (int ni = 0; ni < 4; ++ni)
                acc[mi][ni] = __builtin_amdgcn_mfma_f32_16x16x32_bf16(af[mi], bf[ni], acc[mi][ni], 0, 0, 0);
    }

    const int which = n0 >> 10;   // 0=q 1=k 2=v (block-uniform)
    if (which < 2) {
        u16* outp = (which == 0) ? qo : ko;
        const float lnth = 9.210340371976184f;   // ln(10000)
#pragma unroll
        for (int ni = 0; ni < 4; ++ni) {
            int n = n0 + wn + ni * 16 + l15;
            int hh = (n >> 6) & 15, d = n & 63;
            float invf = __expf(-lnth * (float)(d & 62) * (1.0f / 64.0f));
            float sgn = (d & 1) ? 1.0f : -1.0f;
#pragma unroll
            for (int mi = 0; mi < 4; ++mi) {
#pragma unroll
                for (int i = 0; i < 4; ++i) {
                    int m = m0 + wm + mi * 16 + lg * 4 + i;
                    int bb = m >> 11, s = m & (SEQ - 1);
                    float v = acc[mi][ni][i];
                    float pv = __shfl_xor(v, 1);
                    float sn, cs;
                    __sincosf((float)s * invf, &sn, &cs);
                    float res = v * cs + sgn * pv * sn;
                    if (which == 0) res *= 0.125f;   // 1/sqrt(dk), exact
                    outp[((size_t)(bb * NHEAD + hh) * SEQ + s) * DK + d] = f2bf(res);
                }
            }
        }
    } else {
        // V: per-wave LDS transpose, write (B,H,DK,S)
        __syncthreads();   // staging buffers dead
        u16* sc = &sbuf[w * 64 * 68];
#pragma unroll
        for (int mi = 0; mi < 4; ++mi)
#pragma unroll
            for (int ni = 0; ni < 4; ++ni)
#pragma unroll
                for (int i = 0; i < 4; ++i)
                    sc[(mi * 16 + lg * 4 + i) * 68 + ni * 16 + l15] = f2bf(acc[mi][ni][i]);
        int vcol = n0 - 2048 + wn;          // multiple of 64
        int hh = vcol >> 6;
        int m = m0 + wm, bb = m >> 11, s0 = m & (SEQ - 1);
        u16* dst = vo + ((size_t)(bb * NHEAD + hh) * DK + l) * SEQ + s0;
#pragma unroll
        for (int j8 = 0; j8 < 8; ++j8) {
            u16x8 val;
#pragma unroll
            for (int jj = 0; jj < 8; ++jj) val[jj] = sc[(j8 * 8 + jj) * 68 + l];
            *(u16x8*)&dst[j8 * 8] = val;
        }
    }
}

// ---------------- Flash attention, causal, bf16 MFMA, barrier-free ----------------
// Swapped-operand orientation: S^T = mfma(Kfrag, Qfrag) so each lane owns ONE q-row's
// scores (q = lane&15); softmax is reg-local + 2 shuffles; PV computed as
// O^T = mfma(Vtfrag, Ptfrag) so the rescale scale is lane-local too.
// Explicit 2-stage register pipeline: K(kt+1) and V(kt) loads issued before softmax.
__global__ __launch_bounds__(256) void attn_mfma(
    const u16* __restrict__ qb, const u16* __restrict__ kb,
    const u16* __restrict__ vtb, u16* __restrict__ attnb)
{
    __shared__ __align__(16) u16 Ps_all[4096];   // 4 waves x 16q x 64kv (2KB each)

    const int bh = blockIdx.x;                   // bh fast: uniform-cost dispatch waves
    const int b = bh >> 4, h = bh & 15;
    const int qt = (SEQ / 64 - 1) - blockIdx.y;  // big blocks launch first
    const int qbase = qt * 64;
    const int tid = threadIdx.x, w = tid >> 6, l = tid & 63;
    const int l15 = l & 15, lg = l >> 4;

    // Q B-fragments (col q = l15, k = kk*32 + lg*8..+7), direct from global
    const u16* qlane = qb + ((size_t)bh * SEQ + qbase + w * 16 + l15) * DK + lg * 8;
    bf16x8 bq[2];
    bq[0] = *(const bf16x8*)&qlane[0];
    bq[1] = *(const bf16x8*)&qlane[32];

    const u16* klane = kb + ((size_t)bh * SEQ + l15) * DK + lg * 8;   // + kt*4096 + ni*1024 + kk*32
    const u16* vlane = vtb + ((size_t)bh * DK + l15) * SEQ + lg * 8;  // + n2*16*SEQ + kt*64 + kk*32

    f32x4 zero = {0.f, 0.f, 0.f, 0.f};
    f32x4 ot[4];
#pragma unroll
    for (int i = 0; i < 4; ++i) ot[i] = zero;
    float mrun = -1e30f, lrun = 0.f;     // per-lane: stats of q-row (qbase + w*16 + l15)
    const int qg = qbase + w * 16 + l15;

    char* Psb = (char*)&Ps_all[w * 1024];
    const int swz = (l15 & 7) << 4;

    bf16x8 kfA[4][2], kfB[4][2];

#define LOADK(DST, KT2) { \
    _Pragma("unroll") for (int ni = 0; ni < 4; ++ni) \
    _Pragma("unroll") for (int kk = 0; kk < 2; ++kk) \
        DST[ni][kk] = *(const bf16x8*)&klane[(size_t)(KT2) * 4096 + ni * 1024 + kk * 32]; }

#define BODY(KCUR, KNXT) { \
    const int kc = kt * 64; \
    /* issue V(kt) and K(kt+1) loads early — hidden under QK^T + softmax */ \
    bf16x8 vf[4][2]; \
    _Pragma("unroll") for (int n2 = 0; n2 < 4; ++n2) \
    _Pragma("unroll") for (int kk = 0; kk < 2; ++kk) \
        vf[n2][kk] = *(const bf16x8*)&vlane[(size_t)n2 * 16 * SEQ + kc + kk * 32]; \
    if (kt < qt) LOADK(KNXT, kt + 1); \
    /* S^T[kv][q]: lane holds col q=l15, rows kv = ni*16 + lg*4 + i */ \
    f32x4 s4[4]; \
    _Pragma("unroll") for (int ni = 0; ni < 4; ++ni) { \
        s4[ni] = zero; \
        _Pragma("unroll") for (int kk = 0; kk < 2; ++kk) \
            s4[ni] = __builtin_amdgcn_mfma_f32_16x16x32_bf16(KCUR[ni][kk], bq[kk], s4[ni], 0, 0, 0); \
    } \
    if (kt == qt) { \
        _Pragma("unroll") for (int ni = 0; ni < 4; ++ni) \
        _Pragma("unroll") for (int i = 0; i < 4; ++i) \
            if (kc + ni * 16 + lg * 4 + i > qg) s4[ni][i] = -1e30f; \
    } \
    /* online softmax: all 16 scores for q=l15 are lane-local (x4 lg replicas) */ \
    float mx = -1e30f; \
    _Pragma("unroll") for (int ni = 0; ni < 4; ++ni) \
        mx = fmaxf(mx, fmaxf(fmaxf(s4[ni][0], s4[ni][1]), fmaxf(s4[ni][2], s4[ni][3]))); \
    mx = fmaxf(mx, __shfl_xor(mx, 16)); \
    mx = fmaxf(mx, __shfl_xor(mx, 32)); \
    float mn = fmaxf(mrun, mx); \
    float scl = __expf(mrun - mn); \
    mrun = mn; \
    float rs = 0.f; \
    _Pragma("unroll") for (int ni = 0; ni < 4; ++ni) \
    _Pragma("unroll") for (int ih = 0; ih < 2; ++ih) { \
        float p0 = __expf(s4[ni][2 * ih] - mn); \
        float p1 = __expf(s4[ni][2 * ih + 1] - mn); \
        rs += p0 + p1; \
        unsigned pw = (unsigned)f2bf(p0) | ((unsigned)f2bf(p1) << 16); \
        int bytecol = ni * 32 + lg * 8 + ih * 4; \
        *(unsigned*)(Psb + (l15 << 7) + (bytecol ^ swz)) = pw; \
    } \
    rs += __shfl_xor(rs, 16); \
    rs += __shfl_xor(rs, 32); \
    lrun = lrun * scl + rs; \
    /* P^T B-frags: col q=l15, k = kv = kk*32 + lg*8..+7 */ \
    bf16x8 bp[2]; \
    _Pragma("unroll") for (int kk = 0; kk < 2; ++kk) \
        bp[kk] = *(const bf16x8*)(Psb + (l15 << 7) + ((kk * 64 + lg * 16) ^ swz)); \
    /* O^T[d][q] += V^T x P^T ; rescale lane-local */ \
    _Pragma("unroll") for (int n2 = 0; n2 < 4; ++n2) { \
        _Pragma("unroll") for (int i = 0; i < 4; ++i) ot[n2][i] *= scl; \
        _Pragma("unroll") for (int kk = 0; kk < 2; ++kk) \
            ot[n2] = __builtin_amdgcn_mfma_f32_16x16x32_bf16(vf[n2][kk], bp[kk], ot[n2], 0, 0, 0); \
    } }

    int kt = 0;
    LOADK(kfA, 0);
    for (;;) {
        BODY(kfA, kfB);
        if (++kt > qt) break;
        BODY(kfB, kfA);
        if (++kt > qt) break;
    }
#undef BODY
#undef LOADK

    // epilogue: lane has O^T col q = l15 (lrun lane-local); d = n2*16 + lg*4 + i
    const float invl = 1.0f / lrun;
    u16* orow = attnb + ((size_t)b * SEQ + qg) * D_MODEL + h * DK;
#pragma unroll
    for (int n2 = 0; n2 < 4; ++n2)
#pragma unroll
        for (int ih = 0; ih < 2; ++ih) {
            float r0 = ot[n2][2 * ih] * invl;
            float r1 = ot[n2][2 * ih + 1] * invl;
            unsigned pw = (unsigned)f2bf(r0) | ((unsigned)f2bf(r1) << 16);
            *(unsigned*)&orow[n2 * 16 + lg * 4 + 2 * ih] = pw;
        }
}

// ---------------- Output projection GEMM (M=4096, N=1024, K=1024), fp32 out ----------------
// 2-phase pipelined (double-buffered LDS, one barrier per K-step).
__global__ __launch_bounds__(256) void gemm_proj(
    const u16* __restrict__ A, const u16* __restrict__ B, float* __restrict__ out)
{
    __shared__ __align__(16) u16 sbuf[16384];   // dbuf 2x(As 4096 + Bs 4096)

    const int tid = threadIdx.x, w = tid >> 6, l = tid & 63;
    const int l15 = l & 15, lg = l >> 4;
    const int m0 = blockIdx.x * 128, n0 = blockIdx.y * 128;
    const int wm = (w >> 1) * 64, wn = (w & 1) * 64;

    f32x4 zero = {0.f, 0.f, 0.f, 0.f};
    f32x4 acc[4][4];
#pragma unroll
    for (int i = 0; i < 4; ++i)
#pragma unroll
        for (int j = 0; j < 4; ++j) acc[i][j] = zero;

    auto stage = [&](int k0s, int half) {
        const int hb = half * 8192;
#pragma unroll
        for (int it = 0; it < 2; ++it) {
            int ubase = it * 256 + w * 64;
            int u = ubase + l, row = u >> 2, kq = u & 3;
            gload16(A + (size_t)(m0 + row) * D_MODEL + k0s + kq * 8, &sbuf[hb + ubase * 8]);
        }
#pragma unroll
        for (int it = 0; it < 2; ++it) {
            int ubase = it * 256 + w * 64;
            int u = ubase + l, row = u >> 2, kq = u & 3;
            gload16(B + (size_t)(n0 + row) * D_MODEL + k0s + kq * 8, &sbuf[hb + 4096 + ubase * 8]);
        }
    };

    stage(0, 0);
    int cur = 0;
    for (int k0 = 0; k0 < D_MODEL; k0 += 32, cur ^= 1) {
        __syncthreads();
        if (k0 + 32 < D_MODEL) stage(k0 + 32, cur ^ 1);
        const int hb = cur * 8192;
        bf16x8 af[4], bf[4];
#pragma unroll
        for (int mi = 0; mi < 4; ++mi) af[mi] = *(const bf16x8*)&sbuf[hb + (wm + mi * 16 + l15) * 32 + lg * 8];
#pragma unroll
        for (int ni = 0; ni < 4; ++ni) bf[ni] = *(const bf16x8*)&sbuf[hb + 4096 + (wn + ni * 16 + l15) * 32 + lg * 8];
#pragma unroll
        for (int mi = 0; mi < 4; ++mi)
#pragma unroll
            for (int ni = 0; ni < 4; ++ni)
                acc[mi][ni] = __builtin_amdgcn_mfma_f32_16x16x32_bf16(af[mi], bf[ni], acc[mi][ni], 0, 0, 0);
    }

#pragma unroll
    for (int mi = 0; mi < 4; ++mi)
#pragma unroll
        for (int ni = 0; ni < 4; ++ni)
#pragma unroll
            for (int i = 0; i < 4; ++i) {
                int m = m0 + wm + mi * 16 + lg * 4 + i;
                int n = n0 + wn + ni * 16 + l15;
                out[(size_t)m * D_MODEL + n] = acc[mi][ni][i];
            }
}

extern "C" void kernel_launch(void* const* d_in, const int* in_sizes, int n_in,
                              void* d_out, int out_size, void* d_ws, size_t ws_size,
                              hipStream_t stream) {
    const float* x  = (const float*)d_in[0];
    const float* Wq = (const float*)d_in[1];
    const float* Wk = (const float*)d_in[2];
    const float* Wv = (const float*)d_in[3];
    const float* Wo = (const float*)d_in[4];
    float* out = (float*)d_out;

    u16* ws = (u16*)d_ws;
    const size_t M1 = 1048576;
    u16* xb    = ws;            // 4M u16
    u16* wqkv  = ws + 4 * M1;   // 3M  (Wq|Wk|Wv rows stacked)
    u16* wob   = ws + 7 * M1;   // 1M
    u16* qb    = ws + 8 * M1;   // 4M (B,H,S,DK), scaled by 1/8
    u16* kb    = ws + 12 * M1;  // 4M (B,H,S,DK)
    u16* vtb   = ws + 16 * M1;  // 4M (B,H,DK,S)
    u16* attnb = ws + 20 * M1;  // 4M (B,S,D)

    convert_bf16<<<dim3(4096), dim3(256), 0, stream>>>(x, Wq, Wk, Wv, Wo, xb, wqkv, wob);
    gemm_qkv<<<dim3(MROWS / 128, 3072 / 128), dim3(256), 0, stream>>>(xb, wqkv, qb, kb, vtb);
    attn_mfma<<<dim3(NBATCH * NHEAD, SEQ / 64), dim3(256), 0, stream>>>(qb, kb, vtb, attnb);
    gemm_proj<<<dim3(MROWS / 128, D_MODEL / 128), dim3(256), 0, stream>>>(attnb, wob, out);
}

// Round 8
// 187.962 us; speedup vs baseline: 1.5010x; 1.4067x over previous
//
#include <hip/hip_runtime.h>

#define D_MODEL 1024
#define NHEAD 16
#define DK 64
#define SEQ 2048
#define NBATCH 2
#define MROWS (NBATCH * SEQ)   // 4096

typedef unsigned short u16;
typedef short bf16x8 __attribute__((ext_vector_type(8)));   // 8 bf16 = 4 VGPR
typedef float f32x4 __attribute__((ext_vector_type(4)));
typedef unsigned short u16x8 __attribute__((ext_vector_type(8)));

__device__ __forceinline__ u16 f2bf(float f) {
    union { float f; unsigned u; } v; v.f = f;
    unsigned r = v.u + 0x7FFFu + ((v.u >> 16) & 1u);   // RNE
    return (u16)(r >> 16);
}

__device__ __forceinline__ void gload16(const void* g, void* s) {
    __builtin_amdgcn_global_load_lds((const __attribute__((address_space(1))) void*)g,
                                     (__attribute__((address_space(3))) void*)s, 16, 0, 0);
}

// ---------------- fp32 -> bf16 conversion (x, Wq|Wk|Wv stacked, Wo) ----------------
#define XN 4194304   // 4096*1024
#define WN 1048576   // 1024*1024

__global__ __launch_bounds__(256) void convert_bf16(
    const float* __restrict__ x, const float* __restrict__ wq, const float* __restrict__ wk,
    const float* __restrict__ wv, const float* __restrict__ wo,
    u16* __restrict__ xb, u16* __restrict__ wqkv, u16* __restrict__ wob)
{
    size_t base = ((size_t)blockIdx.x * 256 + threadIdx.x) * 8;
    const float* src; u16* dst;
    if (base < XN)               { src = x  + base;                dst = xb   + base; }
    else if (base < XN + WN)     { src = wq + (base - XN);         dst = wqkv + (base - XN); }
    else if (base < XN + 2*WN)   { src = wk + (base - XN - WN);    dst = wqkv + (base - XN); }
    else if (base < XN + 3*WN)   { src = wv + (base - XN - 2*WN);  dst = wqkv + (base - XN); }
    else                         { src = wo + (base - XN - 3*WN);  dst = wob  + (base - XN - 3*WN); }
    float4 a = *(const float4*)&src[0];
    float4 b = *(const float4*)&src[4];
    u16x8 o;
    o[0] = f2bf(a.x); o[1] = f2bf(a.y); o[2] = f2bf(a.z); o[3] = f2bf(a.w);
    o[4] = f2bf(b.x); o[5] = f2bf(b.y); o[6] = f2bf(b.z); o[7] = f2bf(b.w);
    *(u16x8*)dst = o;
}

// ---------------- QKV GEMM (M=4096, N=3072, K=1024) + RoPE epilogue ----------------
// 2-phase pipelined (double-buffered LDS, one barrier per K-step).
// q,k out: (B,H,S,DK) bf16, q scaled by 0.125.  v out: (B,H,DK,S) bf16 (transposed).
__global__ __launch_bounds__(256) void gemm_qkv(
    const u16* __restrict__ A, const u16* __restrict__ B,
    u16* __restrict__ qo, u16* __restrict__ ko, u16* __restrict__ vo)
{
    __shared__ __align__(16) u16 sbuf[17408];   // dbuf 2x(As 4096 + Bs 4096); epilogue scratch 4*64*68

    const int tid = threadIdx.x, w = tid >> 6, l = tid & 63;
    const int l15 = l & 15, lg = l >> 4;
    const int m0 = blockIdx.x * 128, n0 = blockIdx.y * 128;
    const int wm = (w >> 1) * 64, wn = (w & 1) * 64;

    f32x4 zero = {0.f, 0.f, 0.f, 0.f};
    f32x4 acc[4][4];
#pragma unroll
    for (int i = 0; i < 4; ++i)
#pragma unroll
        for (int j = 0; j < 4; ++j) acc[i][j] = zero;

    auto stage = [&](int k0s, int half) {
        const int hb = half * 8192;
#pragma unroll
        for (int it = 0; it < 2; ++it) {
            int ubase = it * 256 + w * 64;
            int u = ubase + l, row = u >> 2, kq = u & 3;
            gload16(A + (size_t)(m0 + row) * D_MODEL + k0s + kq * 8, &sbuf[hb + ubase * 8]);
        }
#pragma unroll
        for (int it = 0; it < 2; ++it) {
            int ubase = it * 256 + w * 64;
            int u = ubase + l, row = u >> 2, kq = u & 3;
            gload16(B + (size_t)(n0 + row) * D_MODEL + k0s + kq * 8, &sbuf[hb + 4096 + ubase * 8]);
        }
    };

    stage(0, 0);
    int cur = 0;
    for (int k0 = 0; k0 < D_MODEL; k0 += 32, cur ^= 1) {
        __syncthreads();                       // buf[cur] staged (vmcnt drained here)
        if (k0 + 32 < D_MODEL) stage(k0 + 32, cur ^ 1);
        const int hb = cur * 8192;
        bf16x8 af[4], bf[4];
#pragma unroll
        for (int mi = 0; mi < 4; ++mi) af[mi] = *(const bf16x8*)&sbuf[hb + (wm + mi * 16 + l15) * 32 + lg * 8];
#pragma unroll
        for (int ni = 0; ni < 4; ++ni) bf[ni] = *(const bf16x8*)&sbuf[hb + 4096 + (wn + ni * 16 + l15) * 32 + lg * 8];
#pragma unroll
        for (int mi = 0; mi < 4; ++mi)
#pragma unroll
            for (int ni = 0; ni < 4; ++ni)
                acc[mi][ni] = __builtin_amdgcn_mfma_f32_16x16x32_bf16(af[mi], bf[ni], acc[mi][ni], 0, 0, 0);
    }

    const int which = n0 >> 10;   // 0=q 1=k 2=v (block-uniform)
    if (which < 2) {
        u16* outp = (which == 0) ? qo : ko;
        const float lnth = 9.210340371976184f;   // ln(10000)
#pragma unroll
        for (int ni = 0; ni < 4; ++ni) {
            int n = n0 + wn + ni * 16 + l15;
            int hh = (n >> 6) & 15, d = n & 63;
            float invf = __expf(-lnth * (float)(d & 62) * (1.0f / 64.0f));
            float sgn = (d & 1) ? 1.0f : -1.0f;
#pragma unroll
            for (int mi = 0; mi < 4; ++mi) {
#pragma unroll
                for (int i = 0; i < 4; ++i) {
                    int m = m0 + wm + mi * 16 + lg * 4 + i;
                    int bb = m >> 11, s = m & (SEQ - 1);
                    float v = acc[mi][ni][i];
                    float pv = __shfl_xor(v, 1);
                    float sn, cs;
                    __sincosf((float)s * invf, &sn, &cs);
                    float res = v * cs + sgn * pv * sn;
                    if (which == 0) res *= 0.125f;   // 1/sqrt(dk), exact
                    outp[((size_t)(bb * NHEAD + hh) * SEQ + s) * DK + d] = f2bf(res);
                }
            }
        }
    } else {
        // V: per-wave LDS transpose, write (B,H,DK,S)
        __syncthreads();   // staging buffers dead
        u16* sc = &sbuf[w * 64 * 68];
#pragma unroll
        for (int mi = 0; mi < 4; ++mi)
#pragma unroll
            for (int ni = 0; ni < 4; ++ni)
#pragma unroll
                for (int i = 0; i < 4; ++i)
                    sc[(mi * 16 + lg * 4 + i) * 68 + ni * 16 + l15] = f2bf(acc[mi][ni][i]);
        int vcol = n0 - 2048 + wn;          // multiple of 64
        int hh = vcol >> 6;
        int m = m0 + wm, bb = m >> 11, s0 = m & (SEQ - 1);
        u16* dst = vo + ((size_t)(bb * NHEAD + hh) * DK + l) * SEQ + s0;
#pragma unroll
        for (int j8 = 0; j8 < 8; ++j8) {
            u16x8 val;
#pragma unroll
            for (int jj = 0; jj < 8; ++jj) val[jj] = sc[(j8 * 8 + jj) * 68 + l];
            *(u16x8*)&dst[j8 * 8] = val;
        }
    }
}

// ---------------- Flash attention, causal, bf16 MFMA ----------------
// Block = 4 waves x 16 q-rows (QBLK=64). K/V 64x64 tiles staged in LDS,
// double-buffered m97-style (one barrier per tile; stage(kt+1) issued after it).
// Swapped-operand orientation: S^T = mfma(Kfrag, Qfrag) -> lane owns one q-row's
// scores (q = lane&15); softmax reg-local + 2 shuffles; O^T = mfma(Vtfrag, Ptfrag).
// Balanced flat grid: per-CU resident blocks' qt sums are constant (62).
__global__ __launch_bounds__(256, 4) void attn_mfma(
    const u16* __restrict__ qb, const u16* __restrict__ kb,
    const u16* __restrict__ vtb, u16* __restrict__ attnb)
{
    __shared__ __align__(16) u16 Kt[2][4096];    // [buf][64 s][64 d] swizzled
    __shared__ __align__(16) u16 Vt[2][4096];    // [buf][64 d][64 s] swizzled
    __shared__ __align__(16) u16 Ps_all[4096];   // 4 waves x 16q x 64kv (2KB each)

    // balanced (bh, qt) mapping: r in 0..3, g in 0..7 -> qt = {g, 15-g, 16+g, 31-g}[r]
    const int id = blockIdx.x;
    const int bh = id & 31;
    const int g = (id >> 5) & 7, r = id >> 8;
    const int qt = (r == 0) ? g : (r == 1) ? (15 - g) : (r == 2) ? (16 + g) : (31 - g);
    const int b = bh >> 4, h = bh & 15;
    const int qbase = qt * 64;
    const int tid = threadIdx.x, w = tid >> 6, l = tid & 63;
    const int l15 = l & 15, lg = l >> 4;

    // Q B-fragments (col q = l15, k = kk*32 + lg*8..+7), direct from global
    const u16* qlane = qb + ((size_t)bh * SEQ + qbase + w * 16 + l15) * DK + lg * 8;
    bf16x8 bq[2];
    bq[0] = *(const bf16x8*)&qlane[0];
    bq[1] = *(const bf16x8*)&qlane[32];

    const u16* kg = kb + (size_t)bh * SEQ * DK;
    const u16* vg = vtb + (size_t)bh * DK * SEQ;

    f32x4 zero = {0.f, 0.f, 0.f, 0.f};
    f32x4 ot[4];
#pragma unroll
    for (int i = 0; i < 4; ++i) ot[i] = zero;
    float mrun = -1e30f, lrun = 0.f;     // per-lane stats of q-row qg
    const int qg = qbase + w * 16 + l15;

    char* Psb = (char*)&Ps_all[w * 1024];
    const int swz = (l15 & 7) << 4;

    // stage K/V tile kt2 into buffer half (pre-swizzled global source, linear LDS dest)
    auto stageKV = [&](int kt2, int half) {
        const int kc2 = kt2 * 64;
#pragma unroll
        for (int it = 0; it < 2; ++it) {
            int ubase = it * 256 + w * 64;
            int u = ubase + l, rr = u >> 3, cq = u & 7;
            gload16(kg + (size_t)(kc2 + rr) * DK + ((cq ^ (rr & 7)) << 3), &Kt[half][ubase * 8]);
            gload16(vg + (size_t)rr * SEQ + kc2 + ((cq ^ (rr & 7)) << 3), &Vt[half][ubase * 8]);
        }
    };

    stageKV(0, 0);
    int cur = 0;
    for (int kt = 0; kt <= qt; ++kt, cur ^= 1) {
        const int kc = kt * 64;
        __syncthreads();                       // buf[cur] staged (barrier drains vmcnt)
        if (kt < qt) stageKV(kt + 1, cur ^ 1); // prefetch next tile into other half

        // ---- QK^T: S^T[kv][q]; K A-frags from LDS (swizzled, 2-way free) ----
        f32x4 s4[4];
#pragma unroll
        for (int ni = 0; ni < 4; ++ni) {
            s4[ni] = zero;
#pragma unroll
            for (int kk = 0; kk < 2; ++kk) {
                int row = ni * 16 + l15, cq2 = kk * 4 + lg;
                bf16x8 kf = *(const bf16x8*)&Kt[cur][(row * 8 + (cq2 ^ (row & 7))) * 8];
                s4[ni] = __builtin_amdgcn_mfma_f32_16x16x32_bf16(kf, bq[kk], s4[ni], 0, 0, 0);
            }
        }
        if (kt == qt) {   // diagonal tile mask
#pragma unroll
            for (int ni = 0; ni < 4; ++ni)
#pragma unroll
                for (int i = 0; i < 4; ++i)
                    if (kc + ni * 16 + lg * 4 + i > qg) s4[ni][i] = -1e30f;
        }

        // ---- online softmax: 16 scores for q=l15 lane-local (x4 lg replicas) ----
        float mx = -1e30f;
#pragma unroll
        for (int ni = 0; ni < 4; ++ni)
            mx = fmaxf(mx, fmaxf(fmaxf(s4[ni][0], s4[ni][1]), fmaxf(s4[ni][2], s4[ni][3])));
        mx = fmaxf(mx, __shfl_xor(mx, 16));
        mx = fmaxf(mx, __shfl_xor(mx, 32));
        float mn = fmaxf(mrun, mx);
        float scl = __expf(mrun - mn);
        mrun = mn;
        float rs = 0.f;
#pragma unroll
        for (int ni = 0; ni < 4; ++ni)
#pragma unroll
            for (int ih = 0; ih < 2; ++ih) {
                float p0 = __expf(s4[ni][2 * ih] - mn);
                float p1 = __expf(s4[ni][2 * ih + 1] - mn);
                rs += p0 + p1;
                unsigned pw = (unsigned)f2bf(p0) | ((unsigned)f2bf(p1) << 16);
                int bytecol = ni * 32 + lg * 8 + ih * 4;
                *(unsigned*)(Psb + (l15 << 7) + (bytecol ^ swz)) = pw;
            }
        rs += __shfl_xor(rs, 16);
        rs += __shfl_xor(rs, 32);
        lrun = lrun * scl + rs;

        // ---- P^T B-frags from own (wave-local) Ps region ----
        bf16x8 bp[2];
#pragma unroll
        for (int kk = 0; kk < 2; ++kk)
            bp[kk] = *(const bf16x8*)(Psb + (l15 << 7) + ((kk * 64 + lg * 16) ^ swz));

        // ---- PV: O^T[d][q] += V^T x P^T ; rescale lane-local ----
#pragma unroll
        for (int n2 = 0; n2 < 4; ++n2) {
#pragma unroll
            for (int i = 0; i < 4; ++i) ot[n2][i] *= scl;
#pragma unroll
            for (int kk = 0; kk < 2; ++kk) {
                int row = n2 * 16 + l15, cq2 = kk * 4 + lg;
                bf16x8 vf = *(const bf16x8*)&Vt[cur][(row * 8 + (cq2 ^ (row & 7))) * 8];
                ot[n2] = __builtin_amdgcn_mfma_f32_16x16x32_bf16(vf, bp[kk], ot[n2], 0, 0, 0);
            }
        }
    }

    // epilogue: lane has O^T col q (lrun lane-local); d = n2*16 + lg*4 + i
    const float invl = 1.0f / lrun;
    u16* orow = attnb + ((size_t)b * SEQ + qg) * D_MODEL + h * DK;
#pragma unroll
    for (int n2 = 0; n2 < 4; ++n2)
#pragma unroll
        for (int ih = 0; ih < 2; ++ih) {
            float r0 = ot[n2][2 * ih] * invl;
            float r1 = ot[n2][2 * ih + 1] * invl;
            unsigned pw = (unsigned)f2bf(r0) | ((unsigned)f2bf(r1) << 16);
            *(unsigned*)&orow[n2 * 16 + lg * 4 + 2 * ih] = pw;
        }
}

// ---------------- Output projection GEMM (M=4096, N=1024, K=1024), fp32 out ----------------
// 2-phase pipelined (double-buffered LDS, one barrier per K-step).
__global__ __launch_bounds__(256) void gemm_proj(
    const u16* __restrict__ A, const u16* __restrict__ B, float* __restrict__ out)
{
    __shared__ __align__(16) u16 sbuf[16384];   // dbuf 2x(As 4096 + Bs 4096)

    const int tid = threadIdx.x, w = tid >> 6, l = tid & 63;
    const int l15 = l & 15, lg = l >> 4;
    const int m0 = blockIdx.x * 128, n0 = blockIdx.y * 128;
    const int wm = (w >> 1) * 64, wn = (w & 1) * 64;

    f32x4 zero = {0.f, 0.f, 0.f, 0.f};
    f32x4 acc[4][4];
#pragma unroll
    for (int i = 0; i < 4; ++i)
#pragma unroll
        for (int j = 0; j < 4; ++j) acc[i][j] = zero;

    auto stage = [&](int k0s, int half) {
        const int hb = half * 8192;
#pragma unroll
        for (int it = 0; it < 2; ++it) {
            int ubase = it * 256 + w * 64;
            int u = ubase + l, row = u >> 2, kq = u & 3;
            gload16(A + (size_t)(m0 + row) * D_MODEL + k0s + kq * 8, &sbuf[hb + ubase * 8]);
        }
#pragma unroll
        for (int it = 0; it < 2; ++it) {
            int ubase = it * 256 + w * 64;
            int u = ubase + l, row = u >> 2, kq = u & 3;
            gload16(B + (size_t)(n0 + row) * D_MODEL + k0s + kq * 8, &sbuf[hb + 4096 + ubase * 8]);
        }
    };

    stage(0, 0);
    int cur = 0;
    for (int k0 = 0; k0 < D_MODEL; k0 += 32, cur ^= 1) {
        __syncthreads();
        if (k0 + 32 < D_MODEL) stage(k0 + 32, cur ^ 1);
        const int hb = cur * 8192;
        bf16x8 af[4], bf[4];
#pragma unroll
        for (int mi = 0; mi < 4; ++mi) af[mi] = *(const bf16x8*)&sbuf[hb + (wm + mi * 16 + l15) * 32 + lg * 8];
#pragma unroll
        for (int ni = 0; ni < 4; ++ni) bf[ni] = *(const bf16x8*)&sbuf[hb + 4096 + (wn + ni * 16 + l15) * 32 + lg * 8];
#pragma unroll
        for (int mi = 0; mi < 4; ++mi)
#pragma unroll
            for (int ni = 0; ni < 4; ++ni)
                acc[mi][ni] = __builtin_amdgcn_mfma_f32_16x16x32_bf16(af[mi], bf[ni], acc[mi][ni], 0, 0, 0);
    }

#pragma unroll
    for (int mi = 0; mi < 4; ++mi)
#pragma unroll
        for (int ni = 0; ni < 4; ++ni)
#pragma unroll
            for (int i = 0; i < 4; ++i) {
                int m = m0 + wm + mi * 16 + lg * 4 + i;
                int n = n0 + wn + ni * 16 + l15;
                out[(size_t)m * D_MODEL + n] = acc[mi][ni][i];
            }
}

extern "C" void kernel_launch(void* const* d_in, const int* in_sizes, int n_in,
                              void* d_out, int out_size, void* d_ws, size_t ws_size,
                              hipStream_t stream) {
    const float* x  = (const float*)d_in[0];
    const float* Wq = (const float*)d_in[1];
    const float* Wk = (const float*)d_in[2];
    const float* Wv = (const float*)d_in[3];
    const float* Wo = (const float*)d_in[4];
    float* out = (float*)d_out;

    u16* ws = (u16*)d_ws;
    const size_t M1 = 1048576;
    u16* xb    = ws;            // 4M u16
    u16* wqkv  = ws + 4 * M1;   // 3M  (Wq|Wk|Wv rows stacked)
    u16* wob   = ws + 7 * M1;   // 1M
    u16* qb    = ws + 8 * M1;   // 4M (B,H,S,DK), scaled by 1/8
    u16* kb    = ws + 12 * M1;  // 4M (B,H,S,DK)
    u16* vtb   = ws + 16 * M1;  // 4M (B,H,DK,S)
    u16* attnb = ws + 20 * M1;  // 4M (B,S,D)

    convert_bf16<<<dim3(4096), dim3(256), 0, stream>>>(x, Wq, Wk, Wv, Wo, xb, wqkv, wob);
    gemm_qkv<<<dim3(MROWS / 128, 3072 / 128), dim3(256), 0, stream>>>(xb, wqkv, qb, kb, vtb);
    attn_mfma<<<dim3(1024), dim3(256), 0, stream>>>(qb, kb, vtb, attnb);
    gemm_proj<<<dim3(MROWS / 128, D_MODEL / 128), dim3(256), 0, stream>>>(attnb, wob, out);
}

// Round 10
// 186.765 us; speedup vs baseline: 1.5107x; 1.0064x over previous
//
#include <hip/hip_runtime.h>

#define D_MODEL 1024
#define NHEAD 16
#define DK 64
#define SEQ 2048
#define NBATCH 2
#define MROWS (NBATCH * SEQ)   // 4096

typedef unsigned short u16;
typedef short bf16x8 __attribute__((ext_vector_type(8)));   // 8 bf16 = 4 VGPR
typedef float f32x4 __attribute__((ext_vector_type(4)));
typedef unsigned short u16x8 __attribute__((ext_vector_type(8)));

__device__ __forceinline__ u16 f2bf(float f) {
    union { float f; unsigned u; } v; v.f = f;
    unsigned r = v.u + 0x7FFFu + ((v.u >> 16) & 1u);   // RNE
    return (u16)(r >> 16);
}

__device__ __forceinline__ void gload16(const void* g, void* s) {
    __builtin_amdgcn_global_load_lds((const __attribute__((address_space(1))) void*)g,
                                     (__attribute__((address_space(3))) void*)s, 16, 0, 0);
}

// ---------------- fp32 -> bf16 conversion (x, Wq|Wk|Wv stacked, Wo) ----------------
#define XN 4194304   // 4096*1024
#define WN 1048576   // 1024*1024

__global__ __launch_bounds__(256) void convert_bf16(
    const float* __restrict__ x, const float* __restrict__ wq, const float* __restrict__ wk,
    const float* __restrict__ wv, const float* __restrict__ wo,
    u16* __restrict__ xb, u16* __restrict__ wqkv, u16* __restrict__ wob)
{
    size_t base = ((size_t)blockIdx.x * 256 + threadIdx.x) * 8;
    const float* src; u16* dst;
    if (base < XN)               { src = x  + base;                dst = xb   + base; }
    else if (base < XN + WN)     { src = wq + (base - XN);         dst = wqkv + (base - XN); }
    else if (base < XN + 2*WN)   { src = wk + (base - XN - WN);    dst = wqkv + (base - XN); }
    else if (base < XN + 3*WN)   { src = wv + (base - XN - 2*WN);  dst = wqkv + (base - XN); }
    else                         { src = wo + (base - XN - 3*WN);  dst = wob  + (base - XN - 3*WN); }
    float4 a = *(const float4*)&src[0];
    float4 b = *(const float4*)&src[4];
    u16x8 o;
    o[0] = f2bf(a.x); o[1] = f2bf(a.y); o[2] = f2bf(a.z); o[3] = f2bf(a.w);
    o[4] = f2bf(b.x); o[5] = f2bf(b.y); o[6] = f2bf(b.z); o[7] = f2bf(b.w);
    *(u16x8*)dst = o;
}

// ---------------- RoPE trig tables: [d2 0..31][s 0..2047], f32 ----------------
__global__ __launch_bounds__(256) void fill_rope(float* __restrict__ rc, float* __restrict__ rs)
{
    int idx = blockIdx.x * 256 + threadIdx.x;   // 65536 = 32*2048
    int d2 = idx >> 11, s = idx & 2047;
    const float lnth = 9.210340371976184f;      // ln(10000)
    float invf = __expf(-lnth * (float)(2 * d2) * (1.0f / 64.0f));
    float sn, cs;
    __sincosf((float)s * invf, &sn, &cs);
    rc[idx] = cs;
    rs[idx] = sn;
}

// ---------------- QKV GEMM (M=4096, N=3072, K=1024) + RoPE epilogue ----------------
// 2-phase pipelined (double-buffered LDS, one barrier per K-step).
// q,k out: (B,H,S,DK) bf16; q scaled by 0.125*log2(e) (exp2-softmax fold).
// v out: (B,H,DK,S) bf16 (transposed). RoPE via precomputed f32 tables.
__global__ __launch_bounds__(256) void gemm_qkv(
    const u16* __restrict__ A, const u16* __restrict__ B,
    const float* __restrict__ ropec, const float* __restrict__ ropes,
    u16* __restrict__ qo, u16* __restrict__ ko, u16* __restrict__ vo)
{
    __shared__ __align__(16) u16 sbuf[17408];   // dbuf 2x(As 4096 + Bs 4096); epilogue scratch 4*64*68

    const int tid = threadIdx.x, w = tid >> 6, l = tid & 63;
    const int l15 = l & 15, lg = l >> 4;
    const int m0 = blockIdx.x * 128, n0 = blockIdx.y * 128;
    const int wm = (w >> 1) * 64, wn = (w & 1) * 64;

    f32x4 zero = {0.f, 0.f, 0.f, 0.f};
    f32x4 acc[4][4];
#pragma unroll
    for (int i = 0; i < 4; ++i)
#pragma unroll
        for (int j = 0; j < 4; ++j) acc[i][j] = zero;

    auto stage = [&](int k0s, int half) {
        const int hb = half * 8192;
#pragma unroll
        for (int it = 0; it < 2; ++it) {
            int ubase = it * 256 + w * 64;
            int u = ubase + l, row = u >> 2, kq = u & 3;
            gload16(A + (size_t)(m0 + row) * D_MODEL + k0s + kq * 8, &sbuf[hb + ubase * 8]);
        }
#pragma unroll
        for (int it = 0; it < 2; ++it) {
            int ubase = it * 256 + w * 64;
            int u = ubase + l, row = u >> 2, kq = u & 3;
            gload16(B + (size_t)(n0 + row) * D_MODEL + k0s + kq * 8, &sbuf[hb + 4096 + ubase * 8]);
        }
    };

    stage(0, 0);
    int cur = 0;
    for (int k0 = 0; k0 < D_MODEL; k0 += 32, cur ^= 1) {
        __syncthreads();                       // buf[cur] staged (vmcnt drained here)
        if (k0 + 32 < D_MODEL) stage(k0 + 32, cur ^ 1);
        const int hb = cur * 8192;
        bf16x8 af[4], bf[4];
#pragma unroll
        for (int mi = 0; mi < 4; ++mi) af[mi] = *(const bf16x8*)&sbuf[hb + (wm + mi * 16 + l15) * 32 + lg * 8];
#pragma unroll
        for (int ni = 0; ni < 4; ++ni) bf[ni] = *(const bf16x8*)&sbuf[hb + 4096 + (wn + ni * 16 + l15) * 32 + lg * 8];
#pragma unroll
        for (int mi = 0; mi < 4; ++mi)
#pragma unroll
            for (int ni = 0; ni < 4; ++ni)
                acc[mi][ni] = __builtin_amdgcn_mfma_f32_16x16x32_bf16(af[mi], bf[ni], acc[mi][ni], 0, 0, 0);
    }

    const int which = n0 >> 10;   // 0=q 1=k 2=v (block-uniform)
    if (which < 2) {
        u16* outp = (which == 0) ? qo : ko;
        // q gets 0.125 (1/sqrt dk) * log2(e) so attn softmax can use raw exp2
        const float qscale = 0.125f * 1.44269504088896340736f;
#pragma unroll
        for (int ni = 0; ni < 4; ++ni) {
            int n = n0 + wn + ni * 16 + l15;
            int hh = (n >> 6) & 15, d = n & 63;
            const float* rcb = ropec + (d >> 1) * 2048;
            const float* rsb = ropes + (d >> 1) * 2048;
            float sgn = (d & 1) ? 1.0f : -1.0f;
#pragma unroll
            for (int mi = 0; mi < 4; ++mi) {
                int mbase = m0 + wm + mi * 16 + lg * 4;
                int bb = mbase >> 11, sb = mbase & (SEQ - 1);
                float4 c4 = *(const float4*)&rcb[sb];
                float4 s4v = *(const float4*)&rsb[sb];
                float cr[4] = {c4.x, c4.y, c4.z, c4.w};
                float sr[4] = {s4v.x, s4v.y, s4v.z, s4v.w};
#pragma unroll
                for (int i = 0; i < 4; ++i) {
                    float v = acc[mi][ni][i];
                    float pv = __shfl_xor(v, 1);
                    float res = v * cr[i] + sgn * pv * sr[i];
                    if (which == 0) res *= qscale;
                    outp[((size_t)(bb * NHEAD + hh) * SEQ + sb + i) * DK + d] = f2bf(res);
                }
            }
        }
    } else {
        // V: per-wave LDS transpose, write (B,H,DK,S)
        __syncthreads();   // staging buffers dead
        u16* sc = &sbuf[w * 64 * 68];
#pragma unroll
        for (int mi = 0; mi < 4; ++mi)
#pragma unroll
            for (int ni = 0; ni < 4; ++ni)
#pragma unroll
                for (int i = 0; i < 4; ++i)
                    sc[(mi * 16 + lg * 4 + i) * 68 + ni * 16 + l15] = f2bf(acc[mi][ni][i]);
        int vcol = n0 - 2048 + wn;          // multiple of 64
        int hh = vcol >> 6;
        int m = m0 + wm, bb = m >> 11, s0 = m & (SEQ - 1);
        u16* dst = vo + ((size_t)(bb * NHEAD + hh) * DK + l) * SEQ + s0;
#pragma unroll
        for (int j8 = 0; j8 < 8; ++j8) {
            u16x8 val;
#pragma unroll
            for (int jj = 0; jj < 8; ++jj) val[jj] = sc[(j8 * 8 + jj) * 68 + l];
            *(u16x8*)&dst[j8 * 8] = val;
        }
    }
}

// ---------------- Flash attention, causal, bf16 MFMA ----------------
// Scores arrive pre-scaled by log2(e) -> softmax uses raw exp2 (v_exp_f32).
// defer-max (T13, THR=8 log2-units): skip O-rescale while max growth small.
// s_setprio(1) around MFMA clusters (T5). Structure otherwise as round 8.
__global__ __launch_bounds__(256, 4) void attn_mfma(
    const u16* __restrict__ qb, const u16* __restrict__ kb,
    const u16* __restrict__ vtb, u16* __restrict__ attnb)
{
    __shared__ __align__(16) u16 Kt[2][4096];    // [buf][64 s][64 d] swizzled
    __shared__ __align__(16) u16 Vt[2][4096];    // [buf][64 d][64 s] swizzled
    __shared__ __align__(16) u16 Ps_all[4096];   // 4 waves x 16q x 64kv (2KB each)

    // balanced (bh, qt) mapping: r in 0..3, g in 0..7 -> qt = {g, 15-g, 16+g, 31-g}[r]
    const int id = blockIdx.x;
    const int bh = id & 31;
    const int g = (id >> 5) & 7, r = id >> 8;
    const int qt = (r == 0) ? g : (r == 1) ? (15 - g) : (r == 2) ? (16 + g) : (31 - g);
    const int b = bh >> 4, h = bh & 15;
    const int qbase = qt * 64;
    const int tid = threadIdx.x, w = tid >> 6, l = tid & 63;
    const int l15 = l & 15, lg = l >> 4;

    // Q B-fragments (col q = l15, k = kk*32 + lg*8..+7), direct from global
    const u16* qlane = qb + ((size_t)bh * SEQ + qbase + w * 16 + l15) * DK + lg * 8;
    bf16x8 bq[2];
    bq[0] = *(const bf16x8*)&qlane[0];
    bq[1] = *(const bf16x8*)&qlane[32];

    const u16* kg = kb + (size_t)bh * SEQ * DK;
    const u16* vg = vtb + (size_t)bh * DK * SEQ;

    f32x4 zero = {0.f, 0.f, 0.f, 0.f};
    f32x4 ot[4];
#pragma unroll
    for (int i = 0; i < 4; ++i) ot[i] = zero;
    float mrun = -1e30f, lrun = 0.f;     // per-lane stats of q-row qg (log2 units)
    const int qg = qbase + w * 16 + l15;

    char* Psb = (char*)&Ps_all[w * 1024];
    const int swz = (l15 & 7) << 4;

    // stage K/V tile kt2 into buffer half (pre-swizzled global source, linear LDS dest)
    auto stageKV = [&](int kt2, int half) {
        const int kc2 = kt2 * 64;
#pragma unroll
        for (int it = 0; it < 2; ++it) {
            int ubase = it * 256 + w * 64;
            int u = ubase + l, rr = u >> 3, cq = u & 7;
            gload16(kg + (size_t)(kc2 + rr) * DK + ((cq ^ (rr & 7)) << 3), &Kt[half][ubase * 8]);
            gload16(vg + (size_t)rr * SEQ + kc2 + ((cq ^ (rr & 7)) << 3), &Vt[half][ubase * 8]);
        }
    };

    stageKV(0, 0);
    int cur = 0;
    for (int kt = 0; kt <= qt; ++kt, cur ^= 1) {
        const int kc = kt * 64;
        __syncthreads();                       // buf[cur] staged (barrier drains vmcnt)
        if (kt < qt) stageKV(kt + 1, cur ^ 1); // prefetch next tile into other half

        // ---- QK^T: S^T[kv][q]; K A-frags from LDS (swizzled, 2-way free) ----
        f32x4 s4[4];
        __builtin_amdgcn_s_setprio(1);
#pragma unroll
        for (int ni = 0; ni < 4; ++ni) {
            s4[ni] = zero;
#pragma unroll
            for (int kk = 0; kk < 2; ++kk) {
                int row = ni * 16 + l15, cq2 = kk * 4 + lg;
                bf16x8 kf = *(const bf16x8*)&Kt[cur][(row * 8 + (cq2 ^ (row & 7))) * 8];
                s4[ni] = __builtin_amdgcn_mfma_f32_16x16x32_bf16(kf, bq[kk], s4[ni], 0, 0, 0);
            }
        }
        __builtin_amdgcn_s_setprio(0);
        if (kt == qt) {   // diagonal tile mask
#pragma unroll
            for (int ni = 0; ni < 4; ++ni)
#pragma unroll
                for (int i = 0; i < 4; ++i)
                    if (kc + ni * 16 + lg * 4 + i > qg) s4[ni][i] = -1e30f;
        }

        // ---- online softmax (log2 units): 16 scores for q=l15 lane-local ----
        float mx = -1e30f;
#pragma unroll
        for (int ni = 0; ni < 4; ++ni)
            mx = fmaxf(mx, fmaxf(fmaxf(s4[ni][0], s4[ni][1]), fmaxf(s4[ni][2], s4[ni][3])));
        mx = fmaxf(mx, __shfl_xor(mx, 16));
        mx = fmaxf(mx, __shfl_xor(mx, 32));
        // defer-max: only rescale when max grew by > 8 (p bounded by 2^8)
        if (!__all(mx - mrun <= 8.0f)) {
            float mn2 = fmaxf(mrun, mx);
            float scl = __builtin_amdgcn_exp2f(mrun - mn2);
            mrun = mn2;
            lrun *= scl;
#pragma unroll
            for (int n2 = 0; n2 < 4; ++n2)
#pragma unroll
                for (int i = 0; i < 4; ++i) ot[n2][i] *= scl;
        }
        float rs = 0.f;
#pragma unroll
        for (int ni = 0; ni < 4; ++ni)
#pragma unroll
            for (int ih = 0; ih < 2; ++ih) {
                float p0 = __builtin_amdgcn_exp2f(s4[ni][2 * ih] - mrun);
                float p1 = __builtin_amdgcn_exp2f(s4[ni][2 * ih + 1] - mrun);
                rs += p0 + p1;
                unsigned pw = (unsigned)f2bf(p0) | ((unsigned)f2bf(p1) << 16);
                int bytecol = ni * 32 + lg * 8 + ih * 4;
                *(unsigned*)(Psb + (l15 << 7) + (bytecol ^ swz)) = pw;
            }
        rs += __shfl_xor(rs, 16);
        rs += __shfl_xor(rs, 32);
        lrun += rs;

        // ---- P^T B-frags from own (wave-local) Ps region ----
        bf16x8 bp[2];
#pragma unroll
        for (int kk = 0; kk < 2; ++kk)
            bp[kk] = *(const bf16x8*)(Psb + (l15 << 7) + ((kk * 64 + lg * 16) ^ swz));

        // ---- PV: O^T[d][q] += V^T x P^T (pure MFMA cluster) ----
        __builtin_amdgcn_s_setprio(1);
#pragma unroll
        for (int n2 = 0; n2 < 4; ++n2)
#pragma unroll
            for (int kk = 0; kk < 2; ++kk) {
                int row = n2 * 16 + l15, cq2 = kk * 4 + lg;
                bf16x8 vf = *(const bf16x8*)&Vt[cur][(row * 8 + (cq2 ^ (row & 7))) * 8];
                ot[n2] = __builtin_amdgcn_mfma_f32_16x16x32_bf16(vf, bp[kk], ot[n2], 0, 0, 0);
            }
        __builtin_amdgcn_s_setprio(0);
    }

    // epilogue: lane has O^T col q (lrun lane-local); d = n2*16 + lg*4 + i
    const float invl = 1.0f / lrun;
    u16* orow = attnb + ((size_t)b * SEQ + qg) * D_MODEL + h * DK;
#pragma unroll
    for (int n2 = 0; n2 < 4; ++n2)
#pragma unroll
        for (int ih = 0; ih < 2; ++ih) {
            float r0 = ot[n2][2 * ih] * invl;
            float r1 = ot[n2][2 * ih + 1] * invl;
            unsigned pw = (unsigned)f2bf(r0) | ((unsigned)f2bf(r1) << 16);
            *(unsigned*)&orow[n2 * 16 + lg * 4 + 2 * ih] = pw;
        }
}

// ---------------- Output projection GEMM (M=4096, N=1024, K=1024), fp32 out ----------------
// 2-phase pipelined (double-buffered LDS, one barrier per K-step).
__global__ __launch_bounds__(256) void gemm_proj(
    const u16* __restrict__ A, const u16* __restrict__ B, float* __restrict__ out)
{
    __shared__ __align__(16) u16 sbuf[16384];   // dbuf 2x(As 4096 + Bs 4096)

    const int tid = threadIdx.x, w = tid >> 6, l = tid & 63;
    const int l15 = l & 15, lg = l >> 4;
    const int m0 = blockIdx.x * 128, n0 = blockIdx.y * 128;
    const int wm = (w >> 1) * 64, wn = (w & 1) * 64;

    f32x4 zero = {0.f, 0.f, 0.f, 0.f};
    f32x4 acc[4][4];
#pragma unroll
    for (int i = 0; i < 4; ++i)
#pragma unroll
        for (int j = 0; j < 4; ++j) acc[i][j] = zero;

    auto stage = [&](int k0s, int half) {
        const int hb = half * 8192;
#pragma unroll
        for (int it = 0; it < 2; ++it) {
            int ubase = it * 256 + w * 64;
            int u = ubase + l, row = u >> 2, kq = u & 3;
            gload16(A + (size_t)(m0 + row) * D_MODEL + k0s + kq * 8, &sbuf[hb + ubase * 8]);
        }
#pragma unroll
        for (int it = 0; it < 2; ++it) {
            int ubase = it * 256 + w * 64;
            int u = ubase + l, row = u >> 2, kq = u & 3;
            gload16(B + (size_t)(n0 + row) * D_MODEL + k0s + kq * 8, &sbuf[hb + 4096 + ubase * 8]);
        }
    };

    stage(0, 0);
    int cur = 0;
    for (int k0 = 0; k0 < D_MODEL; k0 += 32, cur ^= 1) {
        __syncthreads();
        if (k0 + 32 < D_MODEL) stage(k0 + 32, cur ^ 1);
        const int hb = cur * 8192;
        bf16x8 af[4], bf[4];
#pragma unroll
        for (int mi = 0; mi < 4; ++mi) af[mi] = *(const bf16x8*)&sbuf[hb + (wm + mi * 16 + l15) * 32 + lg * 8];
#pragma unroll
        for (int ni = 0; ni < 4; ++ni) bf[ni] = *(const bf16x8*)&sbuf[hb + 4096 + (wn + ni * 16 + l15) * 32 + lg * 8];
#pragma unroll
        for (int mi = 0; mi < 4; ++mi)
#pragma unroll
            for (int ni = 0; ni < 4; ++ni)
                acc[mi][ni] = __builtin_amdgcn_mfma_f32_16x16x32_bf16(af[mi], bf[ni], acc[mi][ni], 0, 0, 0);
    }

#pragma unroll
    for (int mi = 0; mi < 4; ++mi)
#pragma unroll
        for (int ni = 0; ni < 4; ++ni)
#pragma unroll
            for (int i = 0; i < 4; ++i) {
                int m = m0 + wm + mi * 16 + lg * 4 + i;
                int n = n0 + wn + ni * 16 + l15;
                out[(size_t)m * D_MODEL + n] = acc[mi][ni][i];
            }
}

extern "C" void kernel_launch(void* const* d_in, const int* in_sizes, int n_in,
                              void* d_out, int out_size, void* d_ws, size_t ws_size,
                              hipStream_t stream) {
    const float* x  = (const float*)d_in[0];
    const float* Wq = (const float*)d_in[1];
    const float* Wk = (const float*)d_in[2];
    const float* Wv = (const float*)d_in[3];
    const float* Wo = (const float*)d_in[4];
    float* out = (float*)d_out;

    u16* ws = (u16*)d_ws;
    const size_t M1 = 1048576;
    u16* xb    = ws;            // 4M u16
    u16* wqkv  = ws + 4 * M1;   // 3M  (Wq|Wk|Wv rows stacked)
    u16* wob   = ws + 7 * M1;   // 1M
    u16* qb    = ws + 8 * M1;   // 4M (B,H,S,DK), scaled by 0.125*log2e
    u16* kb    = ws + 12 * M1;  // 4M (B,H,S,DK)
    u16* vtb   = ws + 16 * M1;  // 4M (B,H,DK,S)
    u16* attnb = ws + 20 * M1;  // 4M (B,S,D)
    float* ropec = (float*)(ws + 24 * M1);          // 64K f32
    float* ropes = (float*)(ws + 24 * M1) + 65536;  // 64K f32

    convert_bf16<<<dim3(4096), dim3(256), 0, stream>>>(x, Wq, Wk, Wv, Wo, xb, wqkv, wob);
    fill_rope<<<dim3(256), dim3(256), 0, stream>>>(ropec, ropes);
    gemm_qkv<<<dim3(MROWS / 128, 3072 / 128), dim3(256), 0, stream>>>(xb, wqkv, ropec, ropes, qb, kb, vtb);
    attn_mfma<<<dim3(1024), dim3(256), 0, stream>>>(qb, kb, vtb, attnb);
    gemm_proj<<<dim3(MROWS / 128, D_MODEL / 128), dim3(256), 0, stream>>>(attnb, wob, out);
}